// Round 4
// baseline (278.374 us; speedup 1.0000x reference)
//
#include <hip/hip_runtime.h>
#include <hip/hip_bf16.h>

#define SEQ 4096
#define DIM 1024

using f32x4  = __attribute__((ext_vector_type(4))) float;
using bf16x8 = __attribute__((ext_vector_type(8))) short;

static __device__ __forceinline__ float bf2f(unsigned short u) {
  unsigned int x = ((unsigned int)u) << 16;
  return __builtin_bit_cast(float, x);
}
static __device__ __forceinline__ unsigned short f2bf(float f) {
  unsigned int x = __builtin_bit_cast(unsigned int, f);
  unsigned int r = (x + 0x7fff + ((x >> 16) & 1)) >> 16;  // RNE
  return (unsigned short)r;
}

// ---- x -> bf16; out[:, :1024] = x (fp32); out[:, 1024:2048] = 0 ----
__global__ __launch_bounds__(256) void convert_x_kernel(
    const float* __restrict__ x, unsigned short* __restrict__ xb,
    float* __restrict__ out) {
  int idx = blockIdx.x * 256 + threadIdx.x;  // one thread per 4 floats
  int e = idx * 4;
  int i = e >> 10;
  int d = e & 1023;
  float4 v = *(const float4*)(x + (size_t)e);
  *(float4*)(out + (size_t)i * 2048 + d) = v;
  *(float4*)(out + (size_t)i * 2048 + 1024 + d) = make_float4(0.f, 0.f, 0.f, 0.f);
  ushort4 p;
  p.x = f2bf(v.x); p.y = f2bf(v.y); p.z = f2bf(v.z); p.w = f2bf(v.w);
  *(ushort4*)(xb + (size_t)e) = p;
}

// ---- transpose fp32 [R][C] -> bf16 [C][R] ----
__global__ __launch_bounds__(256) void transpose_f32_to_bf16(
    const float* __restrict__ in, unsigned short* __restrict__ out, int R, int C) {
  __shared__ float tile[32][33];
  int bx = blockIdx.x * 32;  // col base
  int by = blockIdx.y * 32;  // row base
  int tx = threadIdx.x & 31;
  int ty = threadIdx.x >> 5;  // 0..7
#pragma unroll
  for (int r = 0; r < 32; r += 8)
    tile[ty + r][tx] = in[(size_t)(by + ty + r) * C + bx + tx];
  __syncthreads();
#pragma unroll
  for (int r = 0; r < 32; r += 8)
    out[(size_t)(bx + ty + r) * R + by + tx] = f2bf(tile[tx][ty + r]);
}

// ---- transpose bf16: out[c][r] = in[r*ld_in + c] ; r<R, c<C ----
__global__ __launch_bounds__(256) void transpose_bf16_strided(
    const unsigned short* __restrict__ in, int ld_in,
    unsigned short* __restrict__ out, int ld_out, int R, int C) {
  __shared__ unsigned short tile[32][33];
  int bx = blockIdx.x * 32;  // c base
  int by = blockIdx.y * 32;  // r base
  int tx = threadIdx.x & 31;
  int ty = threadIdx.x >> 5;
#pragma unroll
  for (int r = 0; r < 32; r += 8)
    tile[ty + r][tx] = in[(size_t)(by + ty + r) * ld_in + bx + tx];
  __syncthreads();
#pragma unroll
  for (int r = 0; r < 32; r += 8)
    out[(size_t)(bx + ty + r) * ld_out + by + tx] = tile[tx][ty + r];
}

// ---- bias concat [bq | bk | bv] -> bcat[3072] ----
__global__ __launch_bounds__(256) void concat_bias_kernel(
    const float* __restrict__ bq, const float* __restrict__ bk,
    const float* __restrict__ bv, float* __restrict__ bcat) {
  int i = blockIdx.x * 256 + threadIdx.x;
  float v = (i < 1024) ? bq[i] : (i < 2048 ? bk[i - 1024] : bv[i - 2048]);
  bcat[i] = v;
}

// ---- BT GEMM, BK=64, single-buffered global_load_lds staging ----
// MODE 0: fused QKV. bias=bcat, per-col scale (1/32 for gc<1024), bf16 out.
//         XCD slab swizzle (4 i-rows per XCD).
// MODE 1: scores. 528 upper-tri tiles, 66 contiguous per XCD, bf16 out.
// MODE 2: PV split-K (z=4 chunks of 1024); fp32 atomicAdd out; XCD slabs.
template <int MODE>
__global__ __launch_bounds__(256) void gemm_bt(
    const unsigned short* __restrict__ A, int lda,
    const unsigned short* __restrict__ B, int ldb,
    const float* __restrict__ bias,
    unsigned short* __restrict__ Cb, float* __restrict__ Cf,
    int ldc, int ccol, int K) {
  const int tid  = threadIdx.x;
  const int wave = tid >> 6;
  const int lane = tid & 63;
  const int wm = wave >> 1, wn = wave & 1;

  int i0, j0, kstart, kend;
  if (MODE == 1) {
    // 8 XCD chunks of 66 contiguous triangle tiles
    int b = blockIdx.x;
    int t = (b & 7) * 66 + (b >> 3);
    int bi = (int)floorf((65.0f - sqrtf(4225.0f - 8.0f * (float)t)) * 0.5f);
    while (bi > 0 && (bi * (65 - bi)) / 2 > t) --bi;
    while (((bi + 1) * (64 - bi)) / 2 <= t) ++bi;
    int bj = bi + (t - (bi * (65 - bi)) / 2);
    i0 = bi * 128; j0 = bj * 128; kstart = 0; kend = K;
  } else if (MODE == 2) {
    // grid (8,32,4); XCD slab swizzle: xcd owns 4 i-rows
    int lin = blockIdx.x + 8 * (blockIdx.y + 32 * blockIdx.z);
    int xcd = lin & 7, idx = lin >> 3;  // idx in [0,128)
    int by = xcd * 4 + (idx & 3);
    int bx = (idx >> 2) & 7;
    int bz = idx >> 5;  // 0..3
    i0 = by * 128; j0 = bx * 128;
    int kc0 = bz * 1024;
    kend = kc0 + 1024;
    if (kend <= i0) return;           // chunk entirely in zero region
    kstart = (kc0 > i0) ? kc0 : i0;   // Pr cols < i0 are exactly zero
  } else {
    // grid (24,32); XCD slab swizzle: xcd owns 4 i-rows x 24 j-cols
    int lin = blockIdx.x + 24 * blockIdx.y;
    int xcd = lin & 7, idx = lin >> 3;  // idx in [0,96)
    i0 = (xcd * 4 + idx / 24) * 128;
    j0 = (idx % 24) * 128;
    kstart = 0; kend = K;
  }

  __shared__ unsigned short lA[128 * 64];  // 16 KB
  __shared__ unsigned short lB[128 * 64];  // 16 KB

  f32x4 acc[4][4];
#pragma unroll
  for (int a = 0; a < 4; ++a)
#pragma unroll
    for (int b = 0; b < 4; ++b) acc[a][b] = (f32x4){0.f, 0.f, 0.f, 0.f};

  const int l15  = lane & 15;
  const int quad = lane >> 4;
  const int cbase = wave * 256;  // this wave stages chunks [cbase, cbase+256)

  for (int kt = kstart; kt < kend; kt += 64) {
    const unsigned short* gA = A + (size_t)i0 * lda + kt;
    const unsigned short* gB = B + (size_t)j0 * ldb + kt;
    // 128x64 bf16 tile = 1024 x 16B chunks; 8 chunks per row; 4 per thread each for A,B
#pragma unroll
    for (int t = 0; t < 4; ++t) {
      int c  = cbase + t * 64 + lane;
      int r  = c >> 3;
      int co = (c & 7) << 3;
      __builtin_amdgcn_global_load_lds(
          (const __attribute__((address_space(1))) void*)(gA + (size_t)r * lda + co),
          (__attribute__((address_space(3))) void*)(&lA[c * 8]),
          16, 0, 0);
      __builtin_amdgcn_global_load_lds(
          (const __attribute__((address_space(1))) void*)(gB + (size_t)r * ldb + co),
          (__attribute__((address_space(3))) void*)(&lB[c * 8]),
          16, 0, 0);
    }
    __syncthreads();
#pragma unroll
    for (int kf = 0; kf < 2; ++kf) {
      bf16x8 af[4], bfr[4];
#pragma unroll
      for (int mt = 0; mt < 4; ++mt)
        af[mt] = *(const bf16x8*)&lA[(wm * 64 + mt * 16 + l15) * 64 + kf * 32 + quad * 8];
#pragma unroll
      for (int nt = 0; nt < 4; ++nt)
        bfr[nt] = *(const bf16x8*)&lB[(wn * 64 + nt * 16 + l15) * 64 + kf * 32 + quad * 8];
#pragma unroll
      for (int mt = 0; mt < 4; ++mt)
#pragma unroll
        for (int nt = 0; nt < 4; ++nt)
          acc[mt][nt] = __builtin_amdgcn_mfma_f32_16x16x32_bf16(af[mt], bfr[nt], acc[mt][nt], 0, 0, 0);
    }
    __syncthreads();
  }

  // epilogue: C/D layout col=lane&15, row=quad*4+reg
#pragma unroll
  for (int nt = 0; nt < 4; ++nt) {
    int gc = j0 + wn * 64 + nt * 16 + l15;
    float bv = (MODE == 0) ? bias[gc] : 0.0f;
    float scale = (MODE == 0) ? ((gc < 1024) ? 0.03125f : 1.0f) : 1.0f;
#pragma unroll
    for (int mt = 0; mt < 4; ++mt) {
      int gr0 = i0 + wm * 64 + mt * 16 + quad * 4;
#pragma unroll
      for (int r = 0; r < 4; ++r) {
        float v = (acc[mt][nt][r] + bv) * scale;
        if (MODE == 2)
          unsafeAtomicAdd(&Cf[(size_t)(gr0 + r) * ldc + ccol + gc], v);
        else
          Cb[(size_t)(gr0 + r) * ldc + gc] = f2bf(v);
      }
    }
  }
}

// ---- row softmax with anti-causal mask (keep j >= i), in place bf16 ----
__global__ __launch_bounds__(256) void softmax_kernel(unsigned short* __restrict__ sc) {
  const int i    = blockIdx.x;  // row
  const int tid  = threadIdx.x;
  const int lane = tid & 63;
  const int wave = tid >> 6;
  unsigned short* row = sc + (size_t)i * SEQ;

  float vals[16];
  float m = -1e30f;
#pragma unroll
  for (int h = 0; h < 2; ++h) {
    int j0 = (h * 256 + tid) * 8;
    ushort4 r0 = *(const ushort4*)(row + j0);
    ushort4 r1 = *(const ushort4*)(row + j0 + 4);
    unsigned short u[8] = {r0.x, r0.y, r0.z, r0.w, r1.x, r1.y, r1.z, r1.w};
#pragma unroll
    for (int e = 0; e < 8; ++e) {
      float f = bf2f(u[e]);
      vals[h * 8 + e] = f;
      if (j0 + e >= i) m = fmaxf(m, f);
    }
  }
#pragma unroll
  for (int o = 32; o > 0; o >>= 1) m = fmaxf(m, __shfl_xor(m, o));
  __shared__ float redm[4], redl[4];
  if (lane == 0) redm[wave] = m;
  __syncthreads();
  m = fmaxf(fmaxf(redm[0], redm[1]), fmaxf(redm[2], redm[3]));

  float l = 0.f;
#pragma unroll
  for (int h = 0; h < 2; ++h) {
#pragma unroll
    for (int e = 0; e < 8; ++e) {
      int j = (h * 256 + tid) * 8 + e;
      float ev = (j >= i) ? __expf(vals[h * 8 + e] - m) : 0.f;
      vals[h * 8 + e] = ev;
      l += ev;
    }
  }
#pragma unroll
  for (int o = 32; o > 0; o >>= 1) l += __shfl_xor(l, o);
  if (lane == 0) redl[wave] = l;
  __syncthreads();
  l = redl[0] + redl[1] + redl[2] + redl[3];
  float inv = 1.0f / l;

#pragma unroll
  for (int h = 0; h < 2; ++h) {
    int j0 = (h * 256 + tid) * 8;
    ushort4 o0, o1;
    o0.x = f2bf(vals[h * 8 + 0] * inv);
    o0.y = f2bf(vals[h * 8 + 1] * inv);
    o0.z = f2bf(vals[h * 8 + 2] * inv);
    o0.w = f2bf(vals[h * 8 + 3] * inv);
    o1.x = f2bf(vals[h * 8 + 4] * inv);
    o1.y = f2bf(vals[h * 8 + 5] * inv);
    o1.z = f2bf(vals[h * 8 + 6] * inv);
    o1.w = f2bf(vals[h * 8 + 7] * inv);
    *(ushort4*)(row + j0)     = o0;
    *(ushort4*)(row + j0 + 4) = o1;
  }
}

extern "C" void kernel_launch(void* const* d_in, const int* in_sizes, int n_in,
                              void* d_out, int out_size, void* d_ws, size_t ws_size,
                              hipStream_t stream) {
  const float* x  = (const float*)d_in[0];
  const float* Wk = (const float*)d_in[1];
  const float* bk = (const float*)d_in[2];
  const float* Wq = (const float*)d_in[3];
  const float* bq = (const float*)d_in[4];
  const float* Wv = (const float*)d_in[5];
  const float* bv = (const float*)d_in[6];
  float* out = (float*)d_out;

  char* ws = (char*)d_ws;
  unsigned short* Xb   = (unsigned short*)(ws);                  // 8 MB  [4096][1024]
  unsigned short* Wcat = (unsigned short*)(ws + (8ull << 20));   // 6 MB  [3072][1024] (Q|K|V rows)
  unsigned short* QKVb = (unsigned short*)(ws + (14ull << 20));  // 24 MB [4096][3072]
  unsigned short* Vt   = (unsigned short*)(ws + (38ull << 20));  // 8 MB  [1024][4096]
  unsigned short* Pr   = (unsigned short*)(ws + (46ull << 20));  // 32 MB [4096][4096]
  float*          bcat = (float*)(ws + (46ull << 20));           // 12 KB, aliases Pr (dead by then)

  // 1. x -> bf16 ; out[:, :1024] = x ; out[:, 1024:] = 0
  convert_x_kernel<<<SEQ * DIM / 4 / 256, 256, 0, stream>>>(x, Xb, out);

  // 2. W transposes ([in][out] fp32 -> [out][in] bf16) into Wcat sections
  dim3 tg(DIM / 32, DIM / 32);
  transpose_f32_to_bf16<<<tg, 256, 0, stream>>>(Wq, Wcat + 0 * DIM * DIM, DIM, DIM);
  transpose_f32_to_bf16<<<tg, 256, 0, stream>>>(Wk, Wcat + 1 * DIM * DIM, DIM, DIM);
  transpose_f32_to_bf16<<<tg, 256, 0, stream>>>(Wv, Wcat + 2 * DIM * DIM, DIM, DIM);
  concat_bias_kernel<<<12, 256, 0, stream>>>(bq, bk, bv, bcat);

  // 3. fused QKV GEMM: [4096][3072] = Xb @ Wcat^T (+bcat, Q cols scaled 1/32)
  gemm_bt<0><<<dim3(3072 / 128, SEQ / 128), 256, 0, stream>>>(
      Xb, DIM, Wcat, DIM, bcat, QKVb, nullptr, 3072, 0, DIM);

  // 4. Vt[1024][4096] = transpose of V (= QKVb cols 2048:3072)
  transpose_bf16_strided<<<dim3(DIM / 32, SEQ / 32), 256, 0, stream>>>(
      QKVb + 2048, 3072, Vt, SEQ, SEQ, DIM);

  // 5. scores upper-tri tiles: Pr = Qs @ K^T  (528 blocks, 66/XCD)
  gemm_bt<1><<<528, 256, 0, stream>>>(
      QKVb, 3072, QKVb + 1024, 3072, nullptr, Pr, nullptr, SEQ, 0, DIM);

  // 6. masked row softmax in place -> probs bf16 (zeros below diagonal)
  softmax_kernel<<<SEQ, 256, 0, stream>>>(Pr);

  // 7. read = probs @ V -> out[:, 1024:2048] (fp32 atomic, split-K z=4x1024)
  gemm_bt<2><<<dim3(8, 32, 4), 256, 0, stream>>>(
      Pr, SEQ, Vt, SEQ, nullptr, nullptr, out, 2048, 1024, SEQ);
}

// Round 5
// 262.938 us; speedup vs baseline: 1.0587x; 1.0587x over previous
//
#include <hip/hip_runtime.h>
#include <hip/hip_bf16.h>

#define SEQ 4096
#define DIM 1024

using f32x4  = __attribute__((ext_vector_type(4))) float;
using bf16x8 = __attribute__((ext_vector_type(8))) short;

static __device__ __forceinline__ float bf2f(unsigned short u) {
  unsigned int x = ((unsigned int)u) << 16;
  return __builtin_bit_cast(float, x);
}
static __device__ __forceinline__ unsigned short f2bf(float f) {
  unsigned int x = __builtin_bit_cast(unsigned int, f);
  unsigned int r = (x + 0x7fff + ((x >> 16) & 1)) >> 16;  // RNE
  return (unsigned short)r;
}

// ---- x -> bf16; out[:, :1024] = x (fp32); out[:, 1024:2048] = 0 ----
__global__ __launch_bounds__(256) void convert_x_kernel(
    const float* __restrict__ x, unsigned short* __restrict__ xb,
    float* __restrict__ out) {
  int idx = blockIdx.x * 256 + threadIdx.x;  // one thread per 4 floats
  int e = idx * 4;
  int i = e >> 10;
  int d = e & 1023;
  float4 v = *(const float4*)(x + (size_t)e);
  *(float4*)(out + (size_t)i * 2048 + d) = v;
  *(float4*)(out + (size_t)i * 2048 + 1024 + d) = make_float4(0.f, 0.f, 0.f, 0.f);
  ushort4 p;
  p.x = f2bf(v.x); p.y = f2bf(v.y); p.z = f2bf(v.z); p.w = f2bf(v.w);
  *(ushort4*)(xb + (size_t)e) = p;
}

// ---- prep: 3x W transpose ([in][out] f32 -> [out][in] bf16) + bias concat ----
__global__ __launch_bounds__(256) void prep_kernel(
    const float* __restrict__ Wq, const float* __restrict__ Wk,
    const float* __restrict__ Wv, const float* __restrict__ bq,
    const float* __restrict__ bk, const float* __restrict__ bv,
    unsigned short* __restrict__ Wcat, float* __restrict__ bcat) {
  int b = blockIdx.x;
  if (b < 3072) {
    int m  = b >> 10;
    int tt = b & 1023;
    const float* in = (m == 0) ? Wq : (m == 1) ? Wk : Wv;
    unsigned short* out = Wcat + (size_t)m * DIM * DIM;
    __shared__ float tile[32][33];
    int bx = (tt & 31) * 32, by = (tt >> 5) * 32;
    int tx = threadIdx.x & 31, ty = threadIdx.x >> 5;
#pragma unroll
    for (int r = 0; r < 32; r += 8)
      tile[ty + r][tx] = in[(size_t)(by + ty + r) * DIM + bx + tx];
    __syncthreads();
#pragma unroll
    for (int r = 0; r < 32; r += 8)
      out[(size_t)(bx + ty + r) * DIM + by + tx] = f2bf(tile[tx][ty + r]);
  } else {
    int i = (b - 3072) * 256 + threadIdx.x;  // 12 blocks -> 3072 elems
    float v = (i < 1024) ? bq[i] : (i < 2048 ? bk[i - 1024] : bv[i - 2048]);
    bcat[i] = v;
  }
}

// ---- transpose bf16 (V -> Vt) + zero lrow ----
__global__ __launch_bounds__(256) void transpose_v_kernel(
    const unsigned short* __restrict__ in, int ld_in,
    unsigned short* __restrict__ out, int ld_out,
    float* __restrict__ lrow) {
  if (blockIdx.y == 0 && blockIdx.x < 16)
    lrow[blockIdx.x * 256 + threadIdx.x] = 0.0f;
  __shared__ unsigned short tile[32][33];
  int bx = blockIdx.x * 32;  // c base (V col)
  int by = blockIdx.y * 32;  // r base (V row)
  int tx = threadIdx.x & 31;
  int ty = threadIdx.x >> 5;
#pragma unroll
  for (int r = 0; r < 32; r += 8)
    tile[ty + r][tx] = in[(size_t)(by + ty + r) * ld_in + bx + tx];
  __syncthreads();
#pragma unroll
  for (int r = 0; r < 32; r += 8)
    out[(size_t)(bx + ty + r) * ld_out + by + tx] = tile[tx][ty + r];
}

// ---- BT GEMM, BK=32, XOR-swizzled LDS, global_load_lds staging ----
// MODE 0: fused QKV. bias=bcat, scale 1/32 for Q cols, bf16 out. XCD slabs.
// MODE 1: scores. 528 upper-tri tiles (66/XCD). Epilogue: e=exp(S-4), bf16
//         store, per-row sum atomically accumulated into lrow.
// MODE 2: PV split-K (z=4 x 1024); epilogue scales by 1/lrow, fp32 atomicAdd.
template <int MODE>
__global__ __launch_bounds__(256) void gemm_bt(
    const unsigned short* __restrict__ A, int lda,
    const unsigned short* __restrict__ B, int ldb,
    const float* __restrict__ bias,
    unsigned short* __restrict__ Cb, float* __restrict__ Cf,
    float* __restrict__ lrow,
    int ldc, int ccol, int K) {
  const int tid  = threadIdx.x;
  const int wave = tid >> 6;
  const int lane = tid & 63;
  const int wm = wave >> 1, wn = wave & 1;

  int i0, j0, kstart, kend;
  if (MODE == 1) {
    // 8 XCD chunks of 66 contiguous triangle tiles
    int b = blockIdx.x;
    int t = (b & 7) * 66 + (b >> 3);
    int bi = (int)floorf((65.0f - sqrtf(4225.0f - 8.0f * (float)t)) * 0.5f);
    while (bi > 0 && (bi * (65 - bi)) / 2 > t) --bi;
    while (((bi + 1) * (64 - bi)) / 2 <= t) ++bi;
    int bj = bi + (t - (bi * (65 - bi)) / 2);
    i0 = bi * 128; j0 = bj * 128; kstart = 0; kend = K;
  } else if (MODE == 2) {
    // grid (8,32,4); XCD slab swizzle: xcd owns 4 i-rows
    int lin = blockIdx.x + 8 * (blockIdx.y + 32 * blockIdx.z);
    int xcd = lin & 7, idx = lin >> 3;  // idx in [0,128)
    int by = xcd * 4 + (idx & 3);
    int bx = (idx >> 2) & 7;
    int bz = idx >> 5;  // 0..3
    i0 = by * 128; j0 = bx * 128;
    int kc0 = bz * 1024;
    kend = kc0 + 1024;
    if (kend <= i0) return;           // chunk entirely in zero region
    kstart = (kc0 > i0) ? kc0 : i0;   // Pr cols < i0 are exactly zero
  } else {
    // grid (24,32); XCD slab swizzle: xcd owns 4 i-rows x 24 j-cols
    int lin = blockIdx.x + 24 * blockIdx.y;
    int xcd = lin & 7, idx = lin >> 3;  // idx in [0,96)
    i0 = (xcd * 4 + idx / 24) * 128;
    j0 = (idx % 24) * 128;
    kstart = 0; kend = K;
  }

  __shared__ unsigned short lA[128 * 32];  // 8 KB
  __shared__ unsigned short lB[128 * 32];  // 8 KB

  f32x4 acc[4][4];
#pragma unroll
  for (int a = 0; a < 4; ++a)
#pragma unroll
    for (int b = 0; b < 4; ++b) acc[a][b] = (f32x4){0.f, 0.f, 0.f, 0.f};

  const int l15  = lane & 15;
  const int quad = lane >> 4;
  const int cbase = wave * 128;  // this wave stages chunks [cbase, cbase+128)
  const int xsw = (l15 >> 1) & 3;  // read-side XOR swizzle key (row bits 1-2)

  for (int kt = kstart; kt < kend; kt += 32) {
    const unsigned short* gA = A + (size_t)i0 * lda + kt;
    const unsigned short* gB = B + (size_t)j0 * ldb + kt;
#pragma unroll
    for (int t = 0; t < 2; ++t) {
      int c  = cbase + t * 64 + lane;
      int r  = c >> 2;                       // tile row 0..127
      int sl = c & 3;                        // LDS chunk slot within row
      int g  = sl ^ ((r >> 1) & 3);          // global chunk to fetch (swizzle)
      __builtin_amdgcn_global_load_lds(
          (const __attribute__((address_space(1))) void*)(gA + (size_t)r * lda + g * 8),
          (__attribute__((address_space(3))) void*)(&lA[c * 8]),
          16, 0, 0);
      __builtin_amdgcn_global_load_lds(
          (const __attribute__((address_space(1))) void*)(gB + (size_t)r * ldb + g * 8),
          (__attribute__((address_space(3))) void*)(&lB[c * 8]),
          16, 0, 0);
    }
    __syncthreads();
    bf16x8 af[4], bfr[4];
#pragma unroll
    for (int mt = 0; mt < 4; ++mt)
      af[mt] = *(const bf16x8*)&lA[(wm * 64 + mt * 16 + l15) * 32 + (quad ^ xsw) * 8];
#pragma unroll
    for (int nt = 0; nt < 4; ++nt)
      bfr[nt] = *(const bf16x8*)&lB[(wn * 64 + nt * 16 + l15) * 32 + (quad ^ xsw) * 8];
#pragma unroll
    for (int mt = 0; mt < 4; ++mt)
#pragma unroll
      for (int nt = 0; nt < 4; ++nt)
        acc[mt][nt] = __builtin_amdgcn_mfma_f32_16x16x32_bf16(af[mt], bfr[nt], acc[mt][nt], 0, 0, 0);
    __syncthreads();
  }

  // ---- epilogue: C/D layout col=lane&15, row=quad*4+reg ----
  if (MODE == 1) {
    float lsum[4][4];
#pragma unroll
    for (int mt = 0; mt < 4; ++mt)
#pragma unroll
      for (int r = 0; r < 4; ++r) lsum[mt][r] = 0.0f;
#pragma unroll
    for (int nt = 0; nt < 4; ++nt) {
      int gc = j0 + wn * 64 + nt * 16 + l15;
#pragma unroll
      for (int mt = 0; mt < 4; ++mt) {
        int gr0 = i0 + wm * 64 + mt * 16 + quad * 4;
#pragma unroll
        for (int r = 0; r < 4; ++r) {
          int row = gr0 + r;
          float e = (gc >= row) ? __expf(acc[mt][nt][r] - 4.0f) : 0.0f;
          unsigned short eb = f2bf(e);
          Cb[(size_t)row * ldc + gc] = eb;
          lsum[mt][r] += bf2f(eb);  // sum what PV will actually read
        }
      }
    }
#pragma unroll
    for (int mt = 0; mt < 4; ++mt)
#pragma unroll
      for (int r = 0; r < 4; ++r) {
        float s = lsum[mt][r];
        s += __shfl_xor(s, 1);
        s += __shfl_xor(s, 2);
        s += __shfl_xor(s, 4);
        s += __shfl_xor(s, 8);
        if (l15 == 0)
          unsafeAtomicAdd(&lrow[i0 + wm * 64 + mt * 16 + quad * 4 + r], s);
      }
  } else if (MODE == 2) {
    float inv[4][4];
#pragma unroll
    for (int mt = 0; mt < 4; ++mt)
#pragma unroll
      for (int r = 0; r < 4; ++r)
        inv[mt][r] = 1.0f / lrow[i0 + wm * 64 + mt * 16 + quad * 4 + r];
#pragma unroll
    for (int nt = 0; nt < 4; ++nt) {
      int gc = j0 + wn * 64 + nt * 16 + l15;
#pragma unroll
      for (int mt = 0; mt < 4; ++mt) {
        int gr0 = i0 + wm * 64 + mt * 16 + quad * 4;
#pragma unroll
        for (int r = 0; r < 4; ++r)
          unsafeAtomicAdd(&Cf[(size_t)(gr0 + r) * ldc + ccol + gc],
                          acc[mt][nt][r] * inv[mt][r]);
      }
    }
  } else {
#pragma unroll
    for (int nt = 0; nt < 4; ++nt) {
      int gc = j0 + wn * 64 + nt * 16 + l15;
      float bv = bias[gc];
      float scale = (gc < 1024) ? 0.03125f : 1.0f;
#pragma unroll
      for (int mt = 0; mt < 4; ++mt) {
        int gr0 = i0 + wm * 64 + mt * 16 + quad * 4;
#pragma unroll
        for (int r = 0; r < 4; ++r)
          Cb[(size_t)(gr0 + r) * ldc + gc] = f2bf((acc[mt][nt][r] + bv) * scale);
      }
    }
  }
}

extern "C" void kernel_launch(void* const* d_in, const int* in_sizes, int n_in,
                              void* d_out, int out_size, void* d_ws, size_t ws_size,
                              hipStream_t stream) {
  const float* x  = (const float*)d_in[0];
  const float* Wk = (const float*)d_in[1];
  const float* bk = (const float*)d_in[2];
  const float* Wq = (const float*)d_in[3];
  const float* bq = (const float*)d_in[4];
  const float* Wv = (const float*)d_in[5];
  const float* bv = (const float*)d_in[6];
  float* out = (float*)d_out;

  char* ws = (char*)d_ws;
  unsigned short* Xb   = (unsigned short*)(ws);                  // 8 MB  [4096][1024]
  float*          lrow = (float*)(ws);                           // 16 KB, aliases Xb (Xb dead after QKV)
  unsigned short* Wcat = (unsigned short*)(ws + (8ull << 20));   // 6 MB  [3072][1024]
  unsigned short* QKVb = (unsigned short*)(ws + (14ull << 20));  // 24 MB [4096][3072]
  unsigned short* Vt   = (unsigned short*)(ws + (38ull << 20));  // 8 MB  [1024][4096]
  unsigned short* Pr   = (unsigned short*)(ws + (46ull << 20));  // 32 MB [4096][4096]
  float*          bcat = (float*)(ws + (46ull << 20));           // 12 KB, aliases Pr (dead until scores)

  // 1. x -> bf16 ; out[:, :1024] = x ; out[:, 1024:] = 0
  convert_x_kernel<<<SEQ * DIM / 4 / 256, 256, 0, stream>>>(x, Xb, out);

  // 2. W transposes + bias concat (one dispatch)
  prep_kernel<<<3084, 256, 0, stream>>>(Wq, Wk, Wv, bq, bk, bv, Wcat, bcat);

  // 3. fused QKV GEMM: [4096][3072] = Xb @ Wcat^T (+bcat, Q cols scaled 1/32)
  gemm_bt<0><<<dim3(3072 / 128, SEQ / 128), 256, 0, stream>>>(
      Xb, DIM, Wcat, DIM, bcat, QKVb, nullptr, nullptr, 3072, 0, DIM);

  // 4. Vt = V^T (V = QKVb cols 2048:3072); also zeroes lrow (aliases dead Xb)
  transpose_v_kernel<<<dim3(DIM / 32, SEQ / 32), 256, 0, stream>>>(
      QKVb + 2048, 3072, Vt, SEQ, lrow);

  // 5. scores upper-tri tiles + fused exp + row-sum accumulation
  gemm_bt<1><<<528, 256, 0, stream>>>(
      QKVb, 3072, QKVb + 1024, 3072, nullptr, Pr, nullptr, lrow, SEQ, 0, DIM);

  // 6. read = (expS @ V) / l -> out[:, 1024:2048] (fp32 atomic, split-K z=4)
  gemm_bt<2><<<dim3(8, 32, 4), 256, 0, stream>>>(
      Pr, SEQ, Vt, SEQ, nullptr, nullptr, out, lrow, 2048, 1024, SEQ);
}

// Round 6
// 243.630 us; speedup vs baseline: 1.1426x; 1.0792x over previous
//
#include <hip/hip_runtime.h>
#include <hip/hip_bf16.h>

#define SEQ 4096
#define DIM 1024

using f32x4  = __attribute__((ext_vector_type(4))) float;
using bf16x8 = __attribute__((ext_vector_type(8))) short;

static __device__ __forceinline__ float bf2f(unsigned short u) {
  unsigned int x = ((unsigned int)u) << 16;
  return __builtin_bit_cast(float, x);
}
static __device__ __forceinline__ unsigned short f2bf(float f) {
  unsigned int x = __builtin_bit_cast(unsigned int, f);
  unsigned int r = (x + 0x7fff + ((x >> 16) & 1)) >> 16;  // RNE
  return (unsigned short)r;
}

// ---- x -> bf16; out[:, :1024] = x (fp32); out[:, 1024:2048] = 0 ----
__global__ __launch_bounds__(256) void convert_x_kernel(
    const float* __restrict__ x, unsigned short* __restrict__ xb,
    float* __restrict__ out) {
  int idx = blockIdx.x * 256 + threadIdx.x;  // one thread per 4 floats
  int e = idx * 4;
  int i = e >> 10;
  int d = e & 1023;
  float4 v = *(const float4*)(x + (size_t)e);
  *(float4*)(out + (size_t)i * 2048 + d) = v;
  *(float4*)(out + (size_t)i * 2048 + 1024 + d) = make_float4(0.f, 0.f, 0.f, 0.f);
  ushort4 p;
  p.x = f2bf(v.x); p.y = f2bf(v.y); p.z = f2bf(v.z); p.w = f2bf(v.w);
  *(ushort4*)(xb + (size_t)e) = p;
}

// ---- prep: 3x W transpose ([in][out] f32 -> [out][in] bf16) + bias concat ----
__global__ __launch_bounds__(256) void prep_kernel(
    const float* __restrict__ Wq, const float* __restrict__ Wk,
    const float* __restrict__ Wv, const float* __restrict__ bq,
    const float* __restrict__ bk, const float* __restrict__ bv,
    unsigned short* __restrict__ Wcat, float* __restrict__ bcat) {
  int b = blockIdx.x;
  if (b < 3072) {
    int m  = b >> 10;
    int tt = b & 1023;
    const float* in = (m == 0) ? Wq : (m == 1) ? Wk : Wv;
    unsigned short* out = Wcat + (size_t)m * DIM * DIM;
    __shared__ float tile[32][33];
    int bx = (tt & 31) * 32, by = (tt >> 5) * 32;
    int tx = threadIdx.x & 31, ty = threadIdx.x >> 5;
#pragma unroll
    for (int r = 0; r < 32; r += 8)
      tile[ty + r][tx] = in[(size_t)(by + ty + r) * DIM + bx + tx];
    __syncthreads();
#pragma unroll
    for (int r = 0; r < 32; r += 8)
      out[(size_t)(bx + ty + r) * DIM + by + tx] = f2bf(tile[tx][ty + r]);
  } else {
    int i = (b - 3072) * 256 + threadIdx.x;  // 12 blocks -> 3072 elems
    float v = (i < 1024) ? bq[i] : (i < 2048 ? bk[i - 1024] : bv[i - 2048]);
    bcat[i] = v;
  }
}

// ---- transpose bf16 (V -> Vt) + zero lrow ----
__global__ __launch_bounds__(256) void transpose_v_kernel(
    const unsigned short* __restrict__ in, int ld_in,
    unsigned short* __restrict__ out, int ld_out,
    float* __restrict__ lrow) {
  if (blockIdx.y == 0 && blockIdx.x < 16)
    lrow[blockIdx.x * 256 + threadIdx.x] = 0.0f;
  __shared__ unsigned short tile[32][33];
  int bx = blockIdx.x * 32;  // c base (V col)
  int by = blockIdx.y * 32;  // r base (V row)
  int tx = threadIdx.x & 31;
  int ty = threadIdx.x >> 5;
#pragma unroll
  for (int r = 0; r < 32; r += 8)
    tile[ty + r][tx] = in[(size_t)(by + ty + r) * ld_in + bx + tx];
  __syncthreads();
#pragma unroll
  for (int r = 0; r < 32; r += 8)
    out[(size_t)(bx + ty + r) * ld_out + by + tx] = tile[tx][ty + r];
}

// ---- BT GEMM, BK=64, 8-slot XOR-swizzled LDS, global_load_lds staging ----
// MODE 0: fused QKV. bias=bcat, scale 1/32 for Q cols, bf16 out. XCD slabs
//         (work is uniform, slab is safe here).
// MODE 1: scores. 528 upper-tri tiles (66 contiguous/XCD; uniform K work).
//         Epilogue: e=exp(S-4), bf16 store, row-sums atomically into lrow.
// MODE 2: PV split-K (z=4 x 1024). IDENTITY grid mapping (balanced across
//         XCDs -- slab mapping caused a 12x XCD imbalance, R3-R5 regression).
//         Epilogue scales by 1/lrow, fp32 atomicAdd.
template <int MODE>
__global__ __launch_bounds__(256) void gemm_bt(
    const unsigned short* __restrict__ A, int lda,
    const unsigned short* __restrict__ B, int ldb,
    const float* __restrict__ bias,
    unsigned short* __restrict__ Cb, float* __restrict__ Cf,
    float* __restrict__ lrow,
    int ldc, int ccol, int K) {
  const int tid  = threadIdx.x;
  const int wave = tid >> 6;
  const int lane = tid & 63;
  const int wm = wave >> 1, wn = wave & 1;

  int i0, j0, kstart, kend;
  if (MODE == 1) {
    // 8 XCD chunks of 66 contiguous triangle tiles
    int b = blockIdx.x;
    int t = (b & 7) * 66 + (b >> 3);
    int bi = (int)floorf((65.0f - sqrtf(4225.0f - 8.0f * (float)t)) * 0.5f);
    while (bi > 0 && (bi * (65 - bi)) / 2 > t) --bi;
    while (((bi + 1) * (64 - bi)) / 2 <= t) ++bi;
    int bj = bi + (t - (bi * (65 - bi)) / 2);
    i0 = bi * 128; j0 = bj * 128; kstart = 0; kend = K;
  } else if (MODE == 2) {
    // identity mapping: naturally XCD-balanced (bx round-robins XCDs)
    i0 = blockIdx.y * 128; j0 = blockIdx.x * 128;
    int kc0 = blockIdx.z * 1024;
    kend = kc0 + 1024;
    if (kend <= i0) return;           // chunk entirely in zero region
    kstart = (kc0 > i0) ? kc0 : i0;   // Pr cols < i0 are exactly zero
  } else {
    // grid (24,32); XCD slab swizzle: xcd owns 4 i-rows x 24 j-cols
    int lin = blockIdx.x + 24 * blockIdx.y;
    int xcd = lin & 7, idx = lin >> 3;  // idx in [0,96)
    i0 = (xcd * 4 + idx / 24) * 128;
    j0 = (idx % 24) * 128;
    kstart = 0; kend = K;
  }

  __shared__ unsigned short lA[128 * 64];  // 16 KB
  __shared__ unsigned short lB[128 * 64];  // 16 KB

  f32x4 acc[4][4];
#pragma unroll
  for (int a = 0; a < 4; ++a)
#pragma unroll
    for (int b = 0; b < 4; ++b) acc[a][b] = (f32x4){0.f, 0.f, 0.f, 0.f};

  const int l15  = lane & 15;
  const int quad = lane >> 4;
  const int r7   = l15 & 7;       // read-side swizzle key (row low bits)
  const int cbase = wave * 256;   // this wave stages chunks [cbase, cbase+256)

  for (int kt = kstart; kt < kend; kt += 64) {
    const unsigned short* gA = A + (size_t)i0 * lda + kt;
    const unsigned short* gB = B + (size_t)j0 * ldb + kt;
    // 128x64 tile = 1024 chunks of 16B; 8 chunks/row; swizzle: chunk g of
    // row r is stored at slot g ^ (r&7)  (bank = slot*4+w, row-independent)
#pragma unroll
    for (int t = 0; t < 4; ++t) {
      int c  = cbase + t * 64 + lane;
      int r  = c >> 3;                   // tile row 0..127
      int sl = c & 7;                    // LDS slot within row
      int g  = sl ^ (r & 7);             // global chunk to fetch
      __builtin_amdgcn_global_load_lds(
          (const __attribute__((address_space(1))) void*)(gA + (size_t)r * lda + g * 8),
          (__attribute__((address_space(3))) void*)(&lA[c * 8]),
          16, 0, 0);
      __builtin_amdgcn_global_load_lds(
          (const __attribute__((address_space(1))) void*)(gB + (size_t)r * ldb + g * 8),
          (__attribute__((address_space(3))) void*)(&lB[c * 8]),
          16, 0, 0);
    }
    __syncthreads();
#pragma unroll
    for (int kf = 0; kf < 2; ++kf) {
      bf16x8 af[4], bfr[4];
#pragma unroll
      for (int mt = 0; mt < 4; ++mt)
        af[mt] = *(const bf16x8*)&lA[(wm * 64 + mt * 16 + l15) * 64 + ((kf * 4 + quad) ^ r7) * 8];
#pragma unroll
      for (int nt = 0; nt < 4; ++nt)
        bfr[nt] = *(const bf16x8*)&lB[(wn * 64 + nt * 16 + l15) * 64 + ((kf * 4 + quad) ^ r7) * 8];
#pragma unroll
      for (int mt = 0; mt < 4; ++mt)
#pragma unroll
        for (int nt = 0; nt < 4; ++nt)
          acc[mt][nt] = __builtin_amdgcn_mfma_f32_16x16x32_bf16(af[mt], bfr[nt], acc[mt][nt], 0, 0, 0);
    }
    __syncthreads();
  }

  // ---- epilogue: C/D layout col=lane&15, row=quad*4+reg ----
  if (MODE == 1) {
    float lsum[4][4];
#pragma unroll
    for (int mt = 0; mt < 4; ++mt)
#pragma unroll
      for (int r = 0; r < 4; ++r) lsum[mt][r] = 0.0f;
#pragma unroll
    for (int nt = 0; nt < 4; ++nt) {
      int gc = j0 + wn * 64 + nt * 16 + l15;
#pragma unroll
      for (int mt = 0; mt < 4; ++mt) {
        int gr0 = i0 + wm * 64 + mt * 16 + quad * 4;
#pragma unroll
        for (int r = 0; r < 4; ++r) {
          int row = gr0 + r;
          float e = (gc >= row) ? __expf(acc[mt][nt][r] - 4.0f) : 0.0f;
          unsigned short eb = f2bf(e);
          Cb[(size_t)row * ldc + gc] = eb;
          lsum[mt][r] += bf2f(eb);  // sum what PV will actually read
        }
      }
    }
#pragma unroll
    for (int mt = 0; mt < 4; ++mt)
#pragma unroll
      for (int r = 0; r < 4; ++r) {
        float s = lsum[mt][r];
        s += __shfl_xor(s, 1);
        s += __shfl_xor(s, 2);
        s += __shfl_xor(s, 4);
        s += __shfl_xor(s, 8);
        if (l15 == 0)
          unsafeAtomicAdd(&lrow[i0 + wm * 64 + mt * 16 + quad * 4 + r], s);
      }
  } else if (MODE == 2) {
    float inv[4][4];
#pragma unroll
    for (int mt = 0; mt < 4; ++mt)
#pragma unroll
      for (int r = 0; r < 4; ++r)
        inv[mt][r] = 1.0f / lrow[i0 + wm * 64 + mt * 16 + quad * 4 + r];
#pragma unroll
    for (int nt = 0; nt < 4; ++nt) {
      int gc = j0 + wn * 64 + nt * 16 + l15;
#pragma unroll
      for (int mt = 0; mt < 4; ++mt) {
        int gr0 = i0 + wm * 64 + mt * 16 + quad * 4;
#pragma unroll
        for (int r = 0; r < 4; ++r)
          unsafeAtomicAdd(&Cf[(size_t)(gr0 + r) * ldc + ccol + gc],
                          acc[mt][nt][r] * inv[mt][r]);
      }
    }
  } else {
#pragma unroll
    for (int nt = 0; nt < 4; ++nt) {
      int gc = j0 + wn * 64 + nt * 16 + l15;
      float bv = bias[gc];
      float scale = (gc < 1024) ? 0.03125f : 1.0f;
#pragma unroll
      for (int mt = 0; mt < 4; ++mt) {
        int gr0 = i0 + wm * 64 + mt * 16 + quad * 4;
#pragma unroll
        for (int r = 0; r < 4; ++r)
          Cb[(size_t)(gr0 + r) * ldc + gc] = f2bf((acc[mt][nt][r] + bv) * scale);
      }
    }
  }
}

extern "C" void kernel_launch(void* const* d_in, const int* in_sizes, int n_in,
                              void* d_out, int out_size, void* d_ws, size_t ws_size,
                              hipStream_t stream) {
  const float* x  = (const float*)d_in[0];
  const float* Wk = (const float*)d_in[1];
  const float* bk = (const float*)d_in[2];
  const float* Wq = (const float*)d_in[3];
  const float* bq = (const float*)d_in[4];
  const float* Wv = (const float*)d_in[5];
  const float* bv = (const float*)d_in[6];
  float* out = (float*)d_out;

  char* ws = (char*)d_ws;
  unsigned short* Xb   = (unsigned short*)(ws);                  // 8 MB  [4096][1024]
  float*          lrow = (float*)(ws);                           // 16 KB, aliases Xb (Xb dead after QKV)
  unsigned short* Wcat = (unsigned short*)(ws + (8ull << 20));   // 6 MB  [3072][1024]
  unsigned short* QKVb = (unsigned short*)(ws + (14ull << 20));  // 24 MB [4096][3072]
  unsigned short* Vt   = (unsigned short*)(ws + (38ull << 20));  // 8 MB  [1024][4096]
  unsigned short* Pr   = (unsigned short*)(ws + (46ull << 20));  // 32 MB [4096][4096]
  float*          bcat = (float*)(ws + (46ull << 20));           // 12 KB, aliases Pr (dead until scores)

  // 1. x -> bf16 ; out[:, :1024] = x ; out[:, 1024:] = 0
  convert_x_kernel<<<SEQ * DIM / 4 / 256, 256, 0, stream>>>(x, Xb, out);

  // 2. W transposes + bias concat (one dispatch)
  prep_kernel<<<3084, 256, 0, stream>>>(Wq, Wk, Wv, bq, bk, bv, Wcat, bcat);

  // 3. fused QKV GEMM: [4096][3072] = Xb @ Wcat^T (+bcat, Q cols scaled 1/32)
  gemm_bt<0><<<dim3(3072 / 128, SEQ / 128), 256, 0, stream>>>(
      Xb, DIM, Wcat, DIM, bcat, QKVb, nullptr, nullptr, 3072, 0, DIM);

  // 4. Vt = V^T (V = QKVb cols 2048:3072); also zeroes lrow (aliases dead Xb)
  transpose_v_kernel<<<dim3(DIM / 32, SEQ / 32), 256, 0, stream>>>(
      QKVb + 2048, 3072, Vt, SEQ, lrow);

  // 5. scores upper-tri tiles + fused exp + row-sum accumulation
  gemm_bt<1><<<528, 256, 0, stream>>>(
      QKVb, 3072, QKVb + 1024, 3072, nullptr, Pr, nullptr, lrow, SEQ, 0, DIM);

  // 6. read = (expS @ V) / l -> out[:, 1024:2048] (fp32 atomic, split-K z=4)
  gemm_bt<2><<<dim3(8, 32, 4), 256, 0, stream>>>(
      Pr, SEQ, Vt, SEQ, nullptr, nullptr, out, lrow, 2048, 1024, SEQ);
}

// Round 7
// 228.176 us; speedup vs baseline: 1.2200x; 1.0677x over previous
//
#include <hip/hip_runtime.h>
#include <hip/hip_bf16.h>
#include <hip/hip_fp8.h>

#define SEQ 4096
#define DIM 1024

using f32x4  = __attribute__((ext_vector_type(4))) float;
using bf16x8 = __attribute__((ext_vector_type(8))) short;

static __device__ __forceinline__ float bf2f(unsigned short u) {
  unsigned int x = ((unsigned int)u) << 16;
  return __builtin_bit_cast(float, x);
}
static __device__ __forceinline__ unsigned short f2bf(float f) {
  unsigned int x = __builtin_bit_cast(unsigned int, f);
  unsigned int r = (x + 0x7fff + ((x >> 16) & 1)) >> 16;  // RNE
  return (unsigned short)r;
}
static __device__ __forceinline__ unsigned char f2fp8(float f) {
  __hip_fp8_e4m3 h(f);  // OCP e4m3fn
  return h.__x;
}
static __device__ __forceinline__ float fp82f(unsigned char u) {
  __hip_fp8_e4m3 h;
  h.__x = u;
  return (float)h;
}

// ---- x -> bf16; out[:, :1024] = x (fp32); out[:, 1024:2048] = 0 ----
__global__ __launch_bounds__(256) void convert_x_kernel(
    const float* __restrict__ x, unsigned short* __restrict__ xb,
    float* __restrict__ out) {
  int idx = blockIdx.x * 256 + threadIdx.x;  // one thread per 4 floats
  int e = idx * 4;
  int i = e >> 10;
  int d = e & 1023;
  float4 v = *(const float4*)(x + (size_t)e);
  *(float4*)(out + (size_t)i * 2048 + d) = v;
  *(float4*)(out + (size_t)i * 2048 + 1024 + d) = make_float4(0.f, 0.f, 0.f, 0.f);
  ushort4 p;
  p.x = f2bf(v.x); p.y = f2bf(v.y); p.z = f2bf(v.z); p.w = f2bf(v.w);
  *(ushort4*)(xb + (size_t)e) = p;
}

// ---- prep: 3x W transpose ([in][out] f32 -> [out][in] bf16) + bias concat ----
__global__ __launch_bounds__(256) void prep_kernel(
    const float* __restrict__ Wq, const float* __restrict__ Wk,
    const float* __restrict__ Wv, const float* __restrict__ bq,
    const float* __restrict__ bk, const float* __restrict__ bv,
    unsigned short* __restrict__ Wcat, float* __restrict__ bcat) {
  int b = blockIdx.x;
  if (b < 3072) {
    int m  = b >> 10;
    int tt = b & 1023;
    const float* in = (m == 0) ? Wq : (m == 1) ? Wk : Wv;
    unsigned short* out = Wcat + (size_t)m * DIM * DIM;
    __shared__ float tile[32][33];
    int bx = (tt & 31) * 32, by = (tt >> 5) * 32;
    int tx = threadIdx.x & 31, ty = threadIdx.x >> 5;
#pragma unroll
    for (int r = 0; r < 32; r += 8)
      tile[ty + r][tx] = in[(size_t)(by + ty + r) * DIM + bx + tx];
    __syncthreads();
#pragma unroll
    for (int r = 0; r < 32; r += 8)
      out[(size_t)(bx + ty + r) * DIM + by + tx] = f2bf(tile[tx][ty + r]);
  } else {
    int i = (b - 3072) * 256 + threadIdx.x;  // 12 blocks -> 3072 elems
    float v = (i < 1024) ? bq[i] : (i < 2048 ? bk[i - 1024] : bv[i - 2048]);
    bcat[i] = v;
  }
}

// ---- transpose V (bf16 [4096][1024]) -> Vt (fp8 [1024][4096]) + zero lrow ----
__global__ __launch_bounds__(256) void transpose_v_kernel(
    const unsigned short* __restrict__ in, int ld_in,
    unsigned char* __restrict__ out, int ld_out,
    float* __restrict__ lrow) {
  if (blockIdx.y == 0 && blockIdx.x < 16)
    lrow[blockIdx.x * 256 + threadIdx.x] = 0.0f;
  __shared__ unsigned short tile[32][33];
  int bx = blockIdx.x * 32;  // c base (V col)
  int by = blockIdx.y * 32;  // r base (V row)
  int tx = threadIdx.x & 31;
  int ty = threadIdx.x >> 5;
#pragma unroll
  for (int r = 0; r < 32; r += 8)
    tile[ty + r][tx] = in[(size_t)(by + ty + r) * ld_in + bx + tx];
  __syncthreads();
#pragma unroll
  for (int r = 0; r < 32; r += 8)
    out[(size_t)(bx + ty + r) * ld_out + by + tx] = f2fp8(bf2f(tile[tx][ty + r]));
}

// ---- QKV GEMM (bf16, BK=64, 8-slot XOR swizzle, R6-proven K-loop) ----
// C = Xb @ Wcat^T + bcat; epilogue: Q cols -> fp8 (x1/32), K cols -> fp8,
// V cols -> bf16. XCD slab swizzle (uniform work).
__global__ __launch_bounds__(256) void gemm_qkv(
    const unsigned short* __restrict__ A, const unsigned short* __restrict__ B,
    const float* __restrict__ bias,
    unsigned char* __restrict__ Qf8, unsigned char* __restrict__ Kf8,
    unsigned short* __restrict__ Vb) {
  const int tid  = threadIdx.x;
  const int wave = tid >> 6;
  const int lane = tid & 63;
  const int wm = wave >> 1, wn = wave & 1;

  int lin = blockIdx.x + 24 * blockIdx.y;
  int xcd = lin & 7, idx = lin >> 3;  // idx in [0,96)
  const int i0 = (xcd * 4 + idx / 24) * 128;
  const int j0 = (idx % 24) * 128;
  const int lda = DIM, ldb = DIM;

  __shared__ unsigned short lA[128 * 64];  // 16 KB
  __shared__ unsigned short lB[128 * 64];  // 16 KB

  f32x4 acc[4][4];
#pragma unroll
  for (int a = 0; a < 4; ++a)
#pragma unroll
    for (int b = 0; b < 4; ++b) acc[a][b] = (f32x4){0.f, 0.f, 0.f, 0.f};

  const int l15  = lane & 15;
  const int quad = lane >> 4;
  const int r7   = l15 & 7;
  const int cbase = wave * 256;

  for (int kt = 0; kt < DIM; kt += 64) {
    const unsigned short* gA = A + (size_t)i0 * lda + kt;
    const unsigned short* gB = B + (size_t)j0 * ldb + kt;
#pragma unroll
    for (int t = 0; t < 4; ++t) {
      int c  = cbase + t * 64 + lane;
      int r  = c >> 3;
      int sl = c & 7;
      int g  = sl ^ (r & 7);
      __builtin_amdgcn_global_load_lds(
          (const __attribute__((address_space(1))) void*)(gA + (size_t)r * lda + g * 8),
          (__attribute__((address_space(3))) void*)(&lA[c * 8]), 16, 0, 0);
      __builtin_amdgcn_global_load_lds(
          (const __attribute__((address_space(1))) void*)(gB + (size_t)r * ldb + g * 8),
          (__attribute__((address_space(3))) void*)(&lB[c * 8]), 16, 0, 0);
    }
    __syncthreads();
#pragma unroll
    for (int kf = 0; kf < 2; ++kf) {
      bf16x8 af[4], bfr[4];
#pragma unroll
      for (int mt = 0; mt < 4; ++mt)
        af[mt] = *(const bf16x8*)&lA[(wm * 64 + mt * 16 + l15) * 64 + ((kf * 4 + quad) ^ r7) * 8];
#pragma unroll
      for (int nt = 0; nt < 4; ++nt)
        bfr[nt] = *(const bf16x8*)&lB[(wn * 64 + nt * 16 + l15) * 64 + ((kf * 4 + quad) ^ r7) * 8];
#pragma unroll
      for (int mt = 0; mt < 4; ++mt)
#pragma unroll
        for (int nt = 0; nt < 4; ++nt)
          acc[mt][nt] = __builtin_amdgcn_mfma_f32_16x16x32_bf16(af[mt], bfr[nt], acc[mt][nt], 0, 0, 0);
    }
    __syncthreads();
  }

  // epilogue: route to Qf8 / Kf8 / Vb
#pragma unroll
  for (int nt = 0; nt < 4; ++nt) {
    int gc = j0 + wn * 64 + nt * 16 + l15;
    float bv = bias[gc];
#pragma unroll
    for (int mt = 0; mt < 4; ++mt) {
      int gr0 = i0 + wm * 64 + mt * 16 + quad * 4;
#pragma unroll
      for (int r = 0; r < 4; ++r) {
        float v = acc[mt][nt][r] + bv;
        size_t row = (size_t)(gr0 + r);
        if (gc < 1024)
          Qf8[row * DIM + gc] = f2fp8(v * 0.03125f);
        else if (gc < 2048)
          Kf8[row * DIM + (gc - 1024)] = f2fp8(v);
        else
          Vb[row * DIM + (gc - 2048)] = f2bf(v);
      }
    }
  }
}

// ---- fp8 BT GEMM, BK=128, 8-slot XOR swizzle ----
// MODE 1: scores (528 upper-tri tiles, 66/XCD). Epilogue: e=exp(S-4) fp8,
//         row-sums atomically into lrow.
// MODE 2: PV split-K (z=4 x 1024), identity grid (XCD-balanced).
//         Epilogue scales by 1/lrow, fp32 atomicAdd into out.
template <int MODE>
__global__ __launch_bounds__(256) void gemm_fp8(
    const unsigned char* __restrict__ A, int lda,
    const unsigned char* __restrict__ B, int ldb,
    unsigned char* __restrict__ Cb, float* __restrict__ Cf,
    float* __restrict__ lrow, int ldc, int ccol, int K) {
  const int tid  = threadIdx.x;
  const int wave = tid >> 6;
  const int lane = tid & 63;
  const int wm = wave >> 1, wn = wave & 1;

  int i0, j0, kstart, kend;
  if (MODE == 1) {
    int b = blockIdx.x;
    int t = (b & 7) * 66 + (b >> 3);
    int bi = (int)floorf((65.0f - sqrtf(4225.0f - 8.0f * (float)t)) * 0.5f);
    while (bi > 0 && (bi * (65 - bi)) / 2 > t) --bi;
    while (((bi + 1) * (64 - bi)) / 2 <= t) ++bi;
    int bj = bi + (t - (bi * (65 - bi)) / 2);
    i0 = bi * 128; j0 = bj * 128; kstart = 0; kend = K;
  } else {
    i0 = blockIdx.y * 128; j0 = blockIdx.x * 128;
    int kc0 = blockIdx.z * 1024;
    kend = kc0 + 1024;
    if (kend <= i0) return;           // chunk entirely in zero region
    kstart = (kc0 > i0) ? kc0 : i0;   // Pr cols < i0 are exactly zero
  }

  __shared__ unsigned char lA[128 * 128];  // 16 KB
  __shared__ unsigned char lB[128 * 128];  // 16 KB

  f32x4 acc[4][4];
#pragma unroll
  for (int a = 0; a < 4; ++a)
#pragma unroll
    for (int b = 0; b < 4; ++b) acc[a][b] = (f32x4){0.f, 0.f, 0.f, 0.f};

  const int l15  = lane & 15;
  const int quad = lane >> 4;
  const int r7   = l15 & 7;
  const int cbase = wave * 256;  // 1024 chunks of 16B per matrix, 4/thread

  for (int kt = kstart; kt < kend; kt += 128) {
    const unsigned char* gA = A + (size_t)i0 * lda + kt;
    const unsigned char* gB = B + (size_t)j0 * ldb + kt;
    // 128x128B tile; 8 chunks/row; store chunk g of row r at slot g^(r&7)
#pragma unroll
    for (int t = 0; t < 4; ++t) {
      int c  = cbase + t * 64 + lane;
      int r  = c >> 3;
      int sl = c & 7;
      int g  = sl ^ (r & 7);
      __builtin_amdgcn_global_load_lds(
          (const __attribute__((address_space(1))) void*)(gA + (size_t)r * lda + g * 16),
          (__attribute__((address_space(3))) void*)(&lA[c * 16]), 16, 0, 0);
      __builtin_amdgcn_global_load_lds(
          (const __attribute__((address_space(1))) void*)(gB + (size_t)r * ldb + g * 16),
          (__attribute__((address_space(3))) void*)(&lB[c * 16]), 16, 0, 0);
    }
    __syncthreads();
#pragma unroll
    for (int kf = 0; kf < 4; ++kf) {
      long av[4], bvv[4];
#pragma unroll
      for (int mt = 0; mt < 4; ++mt) {
        int row = wm * 64 + mt * 16 + l15;
        int ch  = (kf * 2 + (quad >> 1)) ^ r7;
        av[mt] = *(const long*)&lA[row * 128 + ch * 16 + (quad & 1) * 8];
      }
#pragma unroll
      for (int nt = 0; nt < 4; ++nt) {
        int row = wn * 64 + nt * 16 + l15;
        int ch  = (kf * 2 + (quad >> 1)) ^ r7;
        bvv[nt] = *(const long*)&lB[row * 128 + ch * 16 + (quad & 1) * 8];
      }
#pragma unroll
      for (int mt = 0; mt < 4; ++mt)
#pragma unroll
        for (int nt = 0; nt < 4; ++nt)
          acc[mt][nt] = __builtin_amdgcn_mfma_f32_16x16x32_fp8_fp8(av[mt], bvv[nt], acc[mt][nt], 0, 0, 0);
    }
    __syncthreads();
  }

  // ---- epilogue: C/D layout col=lane&15, row=quad*4+reg ----
  if (MODE == 1) {
    float lsum[4][4];
#pragma unroll
    for (int mt = 0; mt < 4; ++mt)
#pragma unroll
      for (int r = 0; r < 4; ++r) lsum[mt][r] = 0.0f;
#pragma unroll
    for (int nt = 0; nt < 4; ++nt) {
      int gc = j0 + wn * 64 + nt * 16 + l15;
#pragma unroll
      for (int mt = 0; mt < 4; ++mt) {
        int gr0 = i0 + wm * 64 + mt * 16 + quad * 4;
#pragma unroll
        for (int r = 0; r < 4; ++r) {
          int row = gr0 + r;
          float e = (gc >= row) ? __expf(acc[mt][nt][r] - 4.0f) : 0.0f;
          unsigned char eb = f2fp8(e);
          Cb[(size_t)row * ldc + gc] = eb;
          lsum[mt][r] += fp82f(eb);  // sum what PV will actually read
        }
      }
    }
#pragma unroll
    for (int mt = 0; mt < 4; ++mt)
#pragma unroll
      for (int r = 0; r < 4; ++r) {
        float s = lsum[mt][r];
        s += __shfl_xor(s, 1);
        s += __shfl_xor(s, 2);
        s += __shfl_xor(s, 4);
        s += __shfl_xor(s, 8);
        if (l15 == 0)
          unsafeAtomicAdd(&lrow[i0 + wm * 64 + mt * 16 + quad * 4 + r], s);
      }
  } else {
    float inv[4][4];
#pragma unroll
    for (int mt = 0; mt < 4; ++mt)
#pragma unroll
      for (int r = 0; r < 4; ++r)
        inv[mt][r] = 1.0f / lrow[i0 + wm * 64 + mt * 16 + quad * 4 + r];
#pragma unroll
    for (int nt = 0; nt < 4; ++nt) {
      int gc = j0 + wn * 64 + nt * 16 + l15;
#pragma unroll
      for (int mt = 0; mt < 4; ++mt) {
        int gr0 = i0 + wm * 64 + mt * 16 + quad * 4;
#pragma unroll
        for (int r = 0; r < 4; ++r)
          unsafeAtomicAdd(&Cf[(size_t)(gr0 + r) * ldc + ccol + gc],
                          acc[mt][nt][r] * inv[mt][r]);
      }
    }
  }
}

extern "C" void kernel_launch(void* const* d_in, const int* in_sizes, int n_in,
                              void* d_out, int out_size, void* d_ws, size_t ws_size,
                              hipStream_t stream) {
  const float* x  = (const float*)d_in[0];
  const float* Wk = (const float*)d_in[1];
  const float* bk = (const float*)d_in[2];
  const float* Wq = (const float*)d_in[3];
  const float* bq = (const float*)d_in[4];
  const float* Wv = (const float*)d_in[5];
  const float* bv = (const float*)d_in[6];
  float* out = (float*)d_out;

  char* ws = (char*)d_ws;
  unsigned short* Xb   = (unsigned short*)(ws);                  // 8 MB  [4096][1024] bf16
  float*          lrow = (float*)(ws);                           // 16 KB, aliases Xb (dead after QKV)
  unsigned short* Wcat = (unsigned short*)(ws + (8ull << 20));   // 6 MB  [3072][1024] bf16
  float*          bcat = (float*)(ws + (14ull << 20));           // 12 KB
  unsigned char*  Qf8  = (unsigned char*)(ws + (15ull << 20));   // 4 MB  [4096][1024] fp8
  unsigned char*  Kf8  = (unsigned char*)(ws + (19ull << 20));   // 4 MB  [4096][1024] fp8
  unsigned short* Vb   = (unsigned short*)(ws + (23ull << 20));  // 8 MB  [4096][1024] bf16
  unsigned char*  Vt   = (unsigned char*)(ws + (31ull << 20));   // 4 MB  [1024][4096] fp8
  unsigned char*  Pr   = (unsigned char*)(ws + (35ull << 20));   // 16 MB [4096][4096] fp8

  // 1. x -> bf16 ; out[:, :1024] = x ; out[:, 1024:] = 0
  convert_x_kernel<<<SEQ * DIM / 4 / 256, 256, 0, stream>>>(x, Xb, out);

  // 2. W transposes + bias concat (one dispatch)
  prep_kernel<<<3084, 256, 0, stream>>>(Wq, Wk, Wv, bq, bk, bv, Wcat, bcat);

  // 3. fused QKV GEMM (bf16) -> Qf8 (x1/32), Kf8, Vb
  gemm_qkv<<<dim3(24, 32), 256, 0, stream>>>(Xb, Wcat, bcat, Qf8, Kf8, Vb);

  // 4. Vt = V^T as fp8; also zeroes lrow (aliases dead Xb)
  transpose_v_kernel<<<dim3(DIM / 32, SEQ / 32), 256, 0, stream>>>(
      Vb, DIM, Vt, SEQ, lrow);

  // 5. scores upper-tri tiles (fp8) + fused exp + row-sum accumulation
  gemm_fp8<1><<<528, 256, 0, stream>>>(
      Qf8, DIM, Kf8, DIM, Pr, nullptr, lrow, SEQ, 0, DIM);

  // 6. read = (expS @ V) / l -> out[:, 1024:2048] (fp8 mfma, fp32 atomics)
  gemm_fp8<2><<<dim3(8, 32, 4), 256, 0, stream>>>(
      Pr, SEQ, Vt, SEQ, nullptr, out, lrow, 2048, 1024, SEQ);
}